// Round 3
// baseline (3658.723 us; speedup 1.0000x reference)
//
#include <hip/hip_runtime.h>
#include <hip/hip_bf16.h>

using bf16 = __hip_bfloat16;

constexpr int Bd  = 8;
constexpr int Ld  = 4096;
constexpr int Dd  = 512;
constexpr int Hd  = 8;
constexpr int DHd = 64;
constexpr int DFFd= 2048;
constexpr int Ud  = 128;           // TOP_U
constexpr int MLd = Bd * Ld;       // 32768 rows

__device__ __forceinline__ float bf2float(bf16 v) { return __bfloat162float(v); }

__device__ __forceinline__ float rdlane(float v, int l) {
    return __int_as_float(__builtin_amdgcn_readlane(__float_as_int(v), l));
}
__device__ __forceinline__ float wred_sum(float v) {
    #pragma unroll
    for (int o = 32; o > 0; o >>= 1) v += __shfl_xor(v, o);
    return v;
}
__device__ __forceinline__ float wred_max(float v) {
    #pragma unroll
    for (int o = 32; o > 0; o >>= 1) v = fmaxf(v, __shfl_xor(v, o));
    return v;
}
__device__ __forceinline__ float scrub(float v) {       // NaN/Inf -> 0
    return (fabsf(v) < 1e20f) ? v : 0.0f;
}

// ---------------------------------------------------------------- dtype detector
// flags[0] = 1 if float tensors are fp32 on device, 0 if bf16.
// Looks at x (N(0,1), nonzero): in bf16 layout every even uint16 is a sane
// bf16 (exponent ~112..130); in fp32 layout even uint16s are low mantissa
// words (exponent field ~uniform). Vote over 1024 positions.
__global__ void detect_kernel(const void* xraw, int* flags) {
    const unsigned short* u = (const unsigned short*)xraw;
    __shared__ int cnt;
    if (threadIdx.x == 0) cnt = 0;
    __syncthreads();
    int local = 0;
    for (int i = threadIdx.x; i < 1024; i += 256) {
        int e = (u[2 * i] >> 7) & 0xFF;
        if (e >= 96 && e <= 142) local++;
    }
    atomicAdd(&cnt, local);
    __syncthreads();
    if (threadIdx.x == 0) flags[0] = (cnt < 512) ? 1 : 0;
}

// canonicalize any float tensor to bf16
__global__ void conv_kernel(const void* raw, bf16* dst, int n, const int* flags) {
    int i = blockIdx.x * 256 + threadIdx.x;
    if (i >= n) return;
    if (flags[0]) dst[i] = __float2bfloat16(((const float*)raw)[i]);
    else          dst[i] = ((const bf16*)raw)[i];
}

__global__ void zero_kernel(int* p, int n) {
    int i = blockIdx.x * 256 + threadIdx.x;
    if (i < n) p[i] = 0;
}

// sample_idx: handles int32 and int64 device layouts (values < 4096, so
// int64 => odd 32-bit words all zero). Clamped to [0, Ld) for safety.
__global__ void idx_kernel(const void* raw, int* out) {
    const int* r32 = (const int*)raw;
    __shared__ int is64;
    int t = threadIdx.x;                       // 128 threads
    if (t == 0) is64 = 1;
    __syncthreads();
    if (t < 64 && r32[2 * t + 1] != 0) is64 = 0;   // benign same-value race
    __syncthreads();
    int v = is64 ? r32[2 * t] : r32[t];
    out[t] = min(max(v, 0), Ld - 1);
}

// ---------------------------------------------------------------- fp32-accum GEMM
// C[m,n] = sum_k X[m,k]*W[k,n] + bias[n] (optional ReLU). All bf16 in/out.
template<bool RELU>
__launch_bounds__(256)
__global__ void gemm_kernel(const bf16* __restrict__ X, const bf16* __restrict__ W,
                            const bf16* __restrict__ bias, bf16* __restrict__ C,
                            int M, int N, int K)
{
    __shared__ float As[16][68];
    __shared__ float Bs[16][68];
    const int t  = threadIdx.x;
    const int tx = t & 15, ty = t >> 4;
    const int n0 = blockIdx.x * 64, m0 = blockIdx.y * 64;

    float acc[4][4] = {};
    for (int k0 = 0; k0 < K; k0 += 16) {
        {
            int kk = t & 15, mm0 = t >> 4;
            #pragma unroll
            for (int p = 0; p < 4; ++p) {
                int mm = mm0 + p * 16;
                As[kk][mm] = bf2float(X[(size_t)(m0 + mm) * K + k0 + kk]);
            }
            int nn = t & 63, kb0 = t >> 6;
            #pragma unroll
            for (int p = 0; p < 4; ++p) {
                int kk2 = kb0 + p * 4;
                Bs[kk2][nn] = bf2float(W[(size_t)(k0 + kk2) * N + n0 + nn]);
            }
        }
        __syncthreads();
        #pragma unroll
        for (int kk = 0; kk < 16; ++kk) {
            float4 a4 = *(const float4*)&As[kk][ty * 4];
            float4 b4 = *(const float4*)&Bs[kk][tx * 4];
            float av[4] = {a4.x, a4.y, a4.z, a4.w};
            float bv[4] = {b4.x, b4.y, b4.z, b4.w};
            #pragma unroll
            for (int i = 0; i < 4; ++i)
                #pragma unroll
                for (int j = 0; j < 4; ++j)
                    acc[i][j] = fmaf(av[i], bv[j], acc[i][j]);
        }
        __syncthreads();
    }
    #pragma unroll
    for (int i = 0; i < 4; ++i) {
        int m = m0 + ty * 4 + i;
        #pragma unroll
        for (int j = 0; j < 4; ++j) {
            int n = n0 + tx * 4 + j;
            float v = acc[i][j] + bf2float(bias[n]);
            if (RELU) v = fmaxf(v, 0.0f);
            C[(size_t)m * N + n] = __float2bfloat16(v);
        }
    }
}

// ---------------------------------------------------------------- M = max-mean of sampled scores
__launch_bounds__(256)
__global__ void m_kernel(const bf16* __restrict__ Q, const bf16* __restrict__ Kg,
                         const int* __restrict__ sidx, float* __restrict__ Mv)
{
    __shared__ float Qs[64][68];
    __shared__ float Ks[64][132];
    __shared__ float redM[64][16];
    __shared__ float redS[64][16];
    const int t  = threadIdx.x;
    const int bh = blockIdx.y, b = bh >> 3, h = bh & 7;
    const int l0 = blockIdx.x * 64;

    int dl = t & 63, r4 = t >> 6;
    #pragma unroll
    for (int p = 0; p < 16; ++p) {
        int lr = r4 + p * 4;
        Qs[dl][lr] = bf2float(Q[((size_t)(b * Ld + l0 + lr)) * Dd + h * 64 + dl]);
    }
    #pragma unroll
    for (int p = 0; p < 32; ++p) {
        int j = r4 + p * 4;
        Ks[dl][j] = bf2float(Kg[((size_t)(b * Ld + sidx[j])) * Dd + h * 64 + dl]);
    }
    __syncthreads();

    const int tx = t & 15, ty = t >> 4;
    float acc[4][8] = {};
    for (int d = 0; d < 64; ++d) {
        float4 a4  = *(const float4*)&Qs[d][ty * 4];
        float4 b4a = *(const float4*)&Ks[d][tx * 8];
        float4 b4b = *(const float4*)&Ks[d][tx * 8 + 4];
        float av[4] = {a4.x, a4.y, a4.z, a4.w};
        float bv[8] = {b4a.x, b4a.y, b4a.z, b4a.w, b4b.x, b4b.y, b4b.z, b4b.w};
        #pragma unroll
        for (int i = 0; i < 4; ++i)
            #pragma unroll
            for (int j = 0; j < 8; ++j)
                acc[i][j] = fmaf(av[i], bv[j], acc[i][j]);
    }
    #pragma unroll
    for (int i = 0; i < 4; ++i) {
        float rmax = -1e30f, rsum = 0.0f;
        #pragma unroll
        for (int j = 0; j < 8; ++j) { rmax = fmaxf(rmax, acc[i][j]); rsum += acc[i][j]; }
        redM[ty * 4 + i][tx] = rmax;
        redS[ty * 4 + i][tx] = rsum;
    }
    __syncthreads();
    if (t < 64) {
        float m = -1e30f, s = 0.0f;
        #pragma unroll
        for (int q = 0; q < 16; ++q) { m = fmaxf(m, redM[t][q]); s += redS[t][q]; }
        Mv[(size_t)bh * Ld + l0 + t] = m - s * (1.0f / 128.0f);
    }
}

// ---------------------------------------------------------------- top-128 via bitonic sort (desc)
__launch_bounds__(256)
__global__ void topk_kernel(const float* __restrict__ Mv, int* __restrict__ topIdx)
{
    __shared__ float val[4096];
    __shared__ int   idx[4096];
    const int bh = blockIdx.x, t = threadIdx.x;
    for (int i = t; i < 4096; i += 256) { val[i] = Mv[(size_t)bh * Ld + i]; idx[i] = i; }
    __syncthreads();
    for (int k = 2; k <= 4096; k <<= 1) {
        for (int j = k >> 1; j > 0; j >>= 1) {
            for (int i = t; i < 4096; i += 256) {
                int ixj = i ^ j;
                if (ixj > i) {
                    bool up = ((i & k) == 0);
                    float vi = val[i], vj = val[ixj];
                    bool sw = up ? (vi < vj) : (vi > vj);   // descending
                    if (sw) {
                        val[i] = vj; val[ixj] = vi;
                        int tmp = idx[i]; idx[i] = idx[ixj]; idx[ixj] = tmp;
                    }
                }
            }
            __syncthreads();
        }
    }
    if (t < Ud) topIdx[bh * Ud + t] = idx[t];
}

// ---------------------------------------------------------------- per-row sparse-entry list
__global__ void rows_kernel(const int* __restrict__ topIdx, int* __restrict__ rowCnt,
                            int* __restrict__ rowEnt)
{
    const int bh = blockIdx.x, u = threadIdx.x, b = bh >> 3;
    const int lq = topIdx[bh * Ud + u];
    const int row = b * Ld + lq;
    int slot = atomicAdd(&rowCnt[row], 1) & 7;  // <= 8 entries (one per head)
    rowEnt[row * 8 + slot] = bh * Ud + u;
}

// ---------------------------------------------------------------- meanV over L per (b,h,d)
__launch_bounds__(256)
__global__ void meanv_kernel(const bf16* __restrict__ V, float* __restrict__ meanV)
{
    const int bh = blockIdx.x, b = bh >> 3, h = bh & 7, t = threadIdx.x;
    const int d = t & 63, part = t >> 6;
    float s = 0.0f;
    for (int l = part; l < Ld; l += 4)
        s += bf2float(V[((size_t)(b * Ld + l)) * Dd + h * 64 + d]);
    __shared__ float red[256];
    red[t] = s;
    __syncthreads();
    if (t < 64) {
        float tot = red[t] + red[64 + t] + red[128 + t] + red[192 + t];
        meanV[bh * 64 + t] = tot * (1.0f / 4096.0f);
    }
}

// ---------------------------------------------------------------- flash attention for top-U queries
__launch_bounds__(256)
__global__ void attn_kernel(const bf16* __restrict__ Qg, const bf16* __restrict__ Kg,
                            const bf16* __restrict__ Vg, const int* __restrict__ topIdx,
                            float* __restrict__ ctxTop)
{
    __shared__ float Ks[64][65];
    __shared__ float Vs[64][65];
    const int t = threadIdx.x, c = t & 63, w = t >> 6;
    const int ut = blockIdx.x, bh = blockIdx.y, b = bh >> 3, h = bh & 7;

    float Qreg[8];
    #pragma unroll
    for (int rr = 0; rr < 8; ++rr) {
        int u  = ut * 32 + w * 8 + rr;
        int lq = topIdx[bh * Ud + u];
        Qreg[rr] = bf2float(Qg[((size_t)(b * Ld + lq)) * Dd + h * 64 + c]);
    }
    float mrun[8], lrun[8], oacc[8], p[8];
    #pragma unroll
    for (int rr = 0; rr < 8; ++rr) { mrun[rr] = -1e30f; lrun[rr] = 0.0f; oacc[rr] = 0.0f; }

    const int dl = t & 63, r4 = t >> 6;
    for (int kt = 0; kt < 64; ++kt) {
        #pragma unroll
        for (int pp = 0; pp < 16; ++pp) {
            int r = r4 + pp * 4;
            size_t g = ((size_t)(b * Ld + kt * 64 + r)) * Dd + h * 64 + dl;
            Ks[r][dl] = bf2float(Kg[g]);
            Vs[r][dl] = bf2float(Vg[g]);
        }
        __syncthreads();

        float s[8] = {};
        for (int d = 0; d < 64; ++d) {
            float kv = Ks[c][d];
            #pragma unroll
            for (int rr = 0; rr < 8; ++rr)
                s[rr] = fmaf(rdlane(Qreg[rr], d), kv, s[rr]);
        }
        #pragma unroll
        for (int rr = 0; rr < 8; ++rr) {
            float sv   = s[rr] * 0.125f;                 // 1/sqrt(64)
            float smax = wred_max(sv);
            float mnew = fmaxf(mrun[rr], smax);
            float pv   = __expf(sv - mnew);
            float psum = wred_sum(pv);
            float alpha = __expf(mrun[rr] - mnew);
            lrun[rr] = lrun[rr] * alpha + psum;
            mrun[rr] = mnew;
            oacc[rr] *= alpha;
            p[rr] = pv;
        }
        for (int c2 = 0; c2 < 64; ++c2) {
            float vv = Vs[c2][c];
            #pragma unroll
            for (int rr = 0; rr < 8; ++rr)
                oacc[rr] = fmaf(rdlane(p[rr], c2), vv, oacc[rr]);
        }
        __syncthreads();
    }
    #pragma unroll
    for (int rr = 0; rr < 8; ++rr) {
        int u = ut * 32 + w * 8 + rr;
        ctxTop[((size_t)bh * Ud + u) * 64 + c] = scrub(oacc[rr] / lrun[rr]);
    }
}

// ---------------------------------------------------------------- base row: concat(meanV) @ Wo + bo
__launch_bounds__(512)
__global__ void baseout_kernel(const float* __restrict__ meanV, const bf16* __restrict__ Wo,
                               const bf16* __restrict__ bo, float* __restrict__ baseOut)
{
    const int b = blockIdx.x, t = threadIdx.x;   // 512 threads
    __shared__ float mv[512];
    mv[t] = meanV[b * 512 + t];
    __syncthreads();
    float acc = bf2float(bo[t]);
    for (int d = 0; d < 512; ++d)
        acc = fmaf(mv[d], bf2float(Wo[(size_t)d * 512 + t]), acc);
    baseOut[b * 512 + t] = acc;
}

// ---------------------------------------------------------------- per-(bh,u) delta rows (bf16 out)
__launch_bounds__(256)
__global__ void delta_kernel(const float* __restrict__ ctxTop, const float* __restrict__ meanV,
                             const bf16* __restrict__ Wo, bf16* __restrict__ deltaOut)
{
    const int u = blockIdx.x, bh = blockIdx.y, h = bh & 7, t = threadIdx.x;
    __shared__ float diff[64];
    if (t < 64) diff[t] = ctxTop[((size_t)bh * Ud + u) * 64 + t] - meanV[bh * 64 + t];
    __syncthreads();
    for (int n = t; n < 512; n += 256) {
        float acc = 0.0f;
        #pragma unroll 8
        for (int dd = 0; dd < 64; ++dd)
            acc = fmaf(diff[dd], bf2float(Wo[(size_t)(h * 64 + dd) * 512 + n]), acc);
        deltaOut[((size_t)bh * Ud + u) * 512 + n] = __float2bfloat16(acc);
    }
}

// ---------------------------------------------------------------- LayerNorms
__launch_bounds__(256)
__global__ void ln1_kernel(const bf16* __restrict__ x, const float* __restrict__ baseOut,
                           const int* __restrict__ rowCnt, const int* __restrict__ rowEnt,
                           const bf16* __restrict__ deltaOut,
                           const bf16* __restrict__ g, const bf16* __restrict__ bb,
                           bf16* __restrict__ x1)
{
    const int row = blockIdx.x, t = threadIdx.x;
    const int b = row >> 12;
    const size_t base = (size_t)row * 512;
    float v0 = bf2float(x[base + t])       + baseOut[b * 512 + t];
    float v1 = bf2float(x[base + t + 256]) + baseOut[b * 512 + t + 256];
    const int cnt = min(rowCnt[row], 8);
    for (int e = 0; e < cnt; ++e) {
        const bf16* dr = &deltaOut[(size_t)rowEnt[row * 8 + e] * 512];
        v0 += bf2float(dr[t]);
        v1 += bf2float(dr[t + 256]);
    }
    v0 = scrub(v0); v1 = scrub(v1);
    float s = v0 + v1, q = v0 * v0 + v1 * v1;
    s = wred_sum(s); q = wred_sum(q);
    __shared__ float sred[4], qred[4];
    int lane = t & 63, w = t >> 6;
    if (lane == 0) { sred[w] = s; qred[w] = q; }
    __syncthreads();
    float tot  = sred[0] + sred[1] + sred[2] + sred[3];
    float totq = qred[0] + qred[1] + qred[2] + qred[3];
    float mean = tot * (1.0f / 512.0f);
    float var  = fmaxf(totq * (1.0f / 512.0f) - mean * mean, 0.0f);
    float rstd = rsqrtf(var + 1e-6f);
    x1[base + t]       = __float2bfloat16((v0 - mean) * rstd * bf2float(g[t])       + bf2float(bb[t]));
    x1[base + t + 256] = __float2bfloat16((v1 - mean) * rstd * bf2float(g[t + 256]) + bf2float(bb[t + 256]));
}

__launch_bounds__(256)
__global__ void ln2_kernel(const bf16* __restrict__ x1, const bf16* __restrict__ ffn,
                           const bf16* __restrict__ g, const bf16* __restrict__ bb,
                           void* __restrict__ out, const int* __restrict__ flags)
{
    const int row = blockIdx.x, t = threadIdx.x;
    const size_t base = (size_t)row * 512;
    float v0 = bf2float(x1[base + t])       + bf2float(ffn[base + t]);
    float v1 = bf2float(x1[base + t + 256]) + bf2float(ffn[base + t + 256]);
    v0 = scrub(v0); v1 = scrub(v1);
    float s = v0 + v1, q = v0 * v0 + v1 * v1;
    s = wred_sum(s); q = wred_sum(q);
    __shared__ float sred[4], qred[4];
    int lane = t & 63, w = t >> 6;
    if (lane == 0) { sred[w] = s; qred[w] = q; }
    __syncthreads();
    float tot  = sred[0] + sred[1] + sred[2] + sred[3];
    float totq = qred[0] + qred[1] + qred[2] + qred[3];
    float mean = tot * (1.0f / 512.0f);
    float var  = fmaxf(totq * (1.0f / 512.0f) - mean * mean, 0.0f);
    float rstd = rsqrtf(var + 1e-6f);
    float o0 = (v0 - mean) * rstd * bf2float(g[t])       + bf2float(bb[t]);
    float o1 = (v1 - mean) * rstd * bf2float(g[t + 256]) + bf2float(bb[t + 256]);
    if (flags[0]) {
        ((float*)out)[base + t]       = o0;
        ((float*)out)[base + t + 256] = o1;
    } else {
        ((bf16*)out)[base + t]       = __float2bfloat16(o0);
        ((bf16*)out)[base + t + 256] = __float2bfloat16(o1);
    }
}

// ================================================================ launcher
extern "C" void kernel_launch(void* const* d_in, const int* in_sizes, int n_in,
                              void* d_out, int out_size, void* d_ws, size_t ws_size,
                              hipStream_t stream)
{
    const void* sraw = d_in[17];

    // -------- workspace arena (byte offsets)
    const size_t NQ = (size_t)MLd * Dd;          // 16,777,216 elements
    char* w = (char*)d_ws;
    size_t off = 0;
    auto alloc = [&](size_t bytes) { void* p = w + off; off += (bytes + 63) & ~size_t(63); return p; };
    bf16*  Qb      = (bf16*)alloc(NQ * 2);                    // 32 MiB
    bf16*  Kb      = (bf16*)alloc(NQ * 2);                    // 32 MiB
    bf16*  Vb      = (bf16*)alloc(NQ * 2);                    // 32 MiB
    bf16*  xc      = (bf16*)alloc(NQ * 2);                    // 32 MiB canonical x
    bf16*  Wc[6];                                             // Wq,Wk,Wv,Wo,W1f,W2f
    Wc[0] = (bf16*)alloc(Dd * Dd * 2);
    Wc[1] = (bf16*)alloc(Dd * Dd * 2);
    Wc[2] = (bf16*)alloc(Dd * Dd * 2);
    Wc[3] = (bf16*)alloc(Dd * Dd * 2);
    Wc[4] = (bf16*)alloc((size_t)Dd * DFFd * 2);
    Wc[5] = (bf16*)alloc((size_t)DFFd * Dd * 2);
    bf16* bqc = (bf16*)alloc(Dd * 2);
    bf16* bkc = (bf16*)alloc(Dd * 2);
    bf16* bvc = (bf16*)alloc(Dd * 2);
    bf16* boc = (bf16*)alloc(Dd * 2);
    bf16* g1c = (bf16*)alloc(Dd * 2);
    bf16* b1c = (bf16*)alloc(Dd * 2);
    bf16* b1fc= (bf16*)alloc(DFFd * 2);
    bf16* b2fc= (bf16*)alloc(Dd * 2);
    bf16* g2c = (bf16*)alloc(Dd * 2);
    bf16* b2c = (bf16*)alloc(Dd * 2);
    bf16*  deltaOut= (bf16*)alloc((size_t)Bd*Hd*Ud*Dd*2);     // 8 MiB
    float* Mv      = (float*)alloc((size_t)Bd*Hd*Ld*4);       // 1 MiB
    float* ctxTop  = (float*)alloc((size_t)Bd*Hd*Ud*DHd*4);   // 2 MiB
    float* meanV   = (float*)alloc(Bd*Hd*DHd*4);
    float* baseOut = (float*)alloc(Bd*Dd*4);
    int*   topIdx  = (int*)alloc(Bd*Hd*Ud*4);
    int*   sidx    = (int*)alloc(128*4);
    int*   rowCnt  = (int*)alloc(MLd*4);
    int*   rowEnt  = (int*)alloc(MLd*8*4);
    int*   flags   = (int*)alloc(64);
    // aliases (lifetimes disjoint, stream-serialized):
    bf16*  x1b  = Vb;   // written by ln1 after V is dead
    bf16*  h1b  = Qb;   // FFN hidden chunk (8192x2048 bf16 = 32 MiB)
    bf16*  ffnb = Kb;   // FFN out (32768x512 bf16 = 32 MiB)

    if (off > ws_size) return;   // diagnosable: output stays zero

    detect_kernel<<<1, 256, 0, stream>>>(d_in[0], flags);

    auto conv = [&](int i, bf16* dst, int n) {
        conv_kernel<<<(n + 255) / 256, 256, 0, stream>>>(d_in[i], dst, n, flags);
    };
    conv(0,  xc,    (int)NQ);
    conv(1,  Wc[0], Dd * Dd);   conv(2,  bqc, Dd);
    conv(3,  Wc[1], Dd * Dd);   conv(4,  bkc, Dd);
    conv(5,  Wc[2], Dd * Dd);   conv(6,  bvc, Dd);
    conv(7,  Wc[3], Dd * Dd);   conv(8,  boc, Dd);
    conv(9,  g1c, Dd);          conv(10, b1c, Dd);
    conv(11, Wc[4], Dd * DFFd); conv(12, b1fc, DFFd);
    conv(13, Wc[5], DFFd * Dd); conv(14, b2fc, Dd);
    conv(15, g2c, Dd);          conv(16, b2c, Dd);

    zero_kernel<<<(MLd + 255) / 256, 256, 0, stream>>>(rowCnt, MLd);
    idx_kernel<<<1, 128, 0, stream>>>(sraw, sidx);

    // QKV projections
    gemm_kernel<false><<<dim3(8, 512), 256, 0, stream>>>(xc, Wc[0], bqc, Qb, MLd, Dd, Dd);
    gemm_kernel<false><<<dim3(8, 512), 256, 0, stream>>>(xc, Wc[1], bkc, Kb, MLd, Dd, Dd);
    gemm_kernel<false><<<dim3(8, 512), 256, 0, stream>>>(xc, Wc[2], bvc, Vb, MLd, Dd, Dd);

    m_kernel<<<dim3(Ld / 64, Bd * Hd), 256, 0, stream>>>(Qb, Kb, sidx, Mv);
    topk_kernel<<<Bd * Hd, 256, 0, stream>>>(Mv, topIdx);
    rows_kernel<<<Bd * Hd, 128, 0, stream>>>(topIdx, rowCnt, rowEnt);
    meanv_kernel<<<Bd * Hd, 256, 0, stream>>>(Vb, meanV);
    attn_kernel<<<dim3(4, Bd * Hd), 256, 0, stream>>>(Qb, Kb, Vb, topIdx, ctxTop);

    baseout_kernel<<<Bd, 512, 0, stream>>>(meanV, Wc[3], boc, baseOut);
    delta_kernel<<<dim3(Ud, Bd * Hd), 256, 0, stream>>>(ctxTop, meanV, Wc[3], deltaOut);

    ln1_kernel<<<MLd, 256, 0, stream>>>(xc, baseOut, rowCnt, rowEnt, deltaOut, g1c, b1c, x1b);

    // FFN, chunked over rows
    for (int c = 0; c < 4; ++c) {
        gemm_kernel<true ><<<dim3(32, 128), 256, 0, stream>>>(
            x1b + (size_t)c * 8192 * 512, Wc[4], b1fc, h1b, 8192, DFFd, Dd);
        gemm_kernel<false><<<dim3(8, 128), 256, 0, stream>>>(
            h1b, Wc[5], b2fc, ffnb + (size_t)c * 8192 * 512, 8192, Dd, DFFd);
    }

    ln2_kernel<<<MLd, 256, 0, stream>>>(x1b, ffnb, g2c, b2c, d_out, flags);
}

// Round 4
// 1599.313 us; speedup vs baseline: 2.2877x; 2.2877x over previous
//
#include <hip/hip_runtime.h>
#include <hip/hip_bf16.h>

using bf16 = __hip_bfloat16;

constexpr int Bd  = 8;
constexpr int Ld  = 4096;
constexpr int Dd  = 512;
constexpr int Hd  = 8;
constexpr int DHd = 64;
constexpr int DFFd= 2048;
constexpr int Ud  = 128;           // TOP_U
constexpr int MLd = Bd * Ld;       // 32768 rows
constexpr int KSd = 8;             // attention K-split

typedef short          bf16x8 __attribute__((ext_vector_type(8)));
typedef unsigned short u16x8  __attribute__((ext_vector_type(8)));
typedef float          f32x4  __attribute__((ext_vector_type(4)));

__device__ __forceinline__ float bf2float(bf16 v) { return __bfloat162float(v); }

__device__ __forceinline__ float rdlane(float v, int l) {
    return __int_as_float(__builtin_amdgcn_readlane(__float_as_int(v), l));
}
__device__ __forceinline__ float wred_sum(float v) {
    #pragma unroll
    for (int o = 32; o > 0; o >>= 1) v += __shfl_xor(v, o);
    return v;
}
__device__ __forceinline__ float wred_max(float v) {
    #pragma unroll
    for (int o = 32; o > 0; o >>= 1) v = fmaxf(v, __shfl_xor(v, o));
    return v;
}
__device__ __forceinline__ float scrub(float v) {       // NaN/Inf -> 0
    return (fabsf(v) < 1e20f) ? v : 0.0f;
}

// ---------------------------------------------------------------- dtype detector
__global__ void detect_kernel(const void* xraw, int* flags) {
    const unsigned short* u = (const unsigned short*)xraw;
    __shared__ int cnt;
    if (threadIdx.x == 0) cnt = 0;
    __syncthreads();
    int local = 0;
    for (int i = threadIdx.x; i < 1024; i += 256) {
        int e = (u[2 * i] >> 7) & 0xFF;
        if (e >= 96 && e <= 142) local++;
    }
    atomicAdd(&cnt, local);
    __syncthreads();
    if (threadIdx.x == 0) flags[0] = (cnt < 512) ? 1 : 0;
}

// canonicalize any float tensor to bf16
__global__ void conv_kernel(const void* raw, bf16* dst, int n, const int* flags) {
    int i = blockIdx.x * 256 + threadIdx.x;
    if (i >= n) return;
    if (flags[0]) dst[i] = __float2bfloat16(((const float*)raw)[i]);
    else          dst[i] = ((const bf16*)raw)[i];
}

// canonicalize + transpose weight: in W[K][N] -> out WT[N][K] (bf16)
__global__ void convT_kernel(const void* raw, bf16* dst, int K, int N, const int* flags) {
    __shared__ bf16 tile[32][33];
    const int k0 = blockIdx.y * 32, n0 = blockIdx.x * 32;
    const int tx = threadIdx.x & 31, ty = threadIdx.x >> 5;     // 32 x 8
    #pragma unroll
    for (int p = 0; p < 4; ++p) {
        int k = k0 + ty + p * 8, n = n0 + tx;
        float v = flags[0] ? ((const float*)raw)[(size_t)k * N + n]
                           : bf2float(((const bf16*)raw)[(size_t)k * N + n]);
        tile[ty + p * 8][tx] = __float2bfloat16(v);
    }
    __syncthreads();
    #pragma unroll
    for (int p = 0; p < 4; ++p) {
        int n = n0 + ty + p * 8, k = k0 + tx;
        dst[(size_t)n * K + k] = tile[tx][ty + p * 8];
    }
}

__global__ void zero_kernel(int* p, int n) {
    int i = blockIdx.x * 256 + threadIdx.x;
    if (i < n) p[i] = 0;
}

// sample_idx: int32 or int64 device layout; clamped to [0, Ld)
__global__ void idx_kernel(const void* raw, int* out) {
    const int* r32 = (const int*)raw;
    __shared__ int is64;
    int t = threadIdx.x;                       // 128 threads
    if (t == 0) is64 = 1;
    __syncthreads();
    if (t < 64 && r32[2 * t + 1] != 0) is64 = 0;
    __syncthreads();
    int v = is64 ? r32[2 * t] : r32[t];
    out[t] = min(max(v, 0), Ld - 1);
}

// ---------------------------------------------------------------- MFMA GEMM
// C[m,n] = sum_k X[m,k]*WT[n,k] + bias[n]; 128x128 tile, BK=32, 4 waves.
// LDS rows stride 40 bf16 (80B): ds_read_b128 fragment reads spread evenly
// over all 32 banks (20 words/row, odd multiple of 4).
template<bool RELU>
__launch_bounds__(256)
__global__ void mfma_gemm(const bf16* __restrict__ X, const bf16* __restrict__ WT,
                          const bf16* __restrict__ bias, bf16* __restrict__ C,
                          int M, int N, int K)
{
    constexpr int LS = 40;                      // LDS row stride (bf16 elems)
    __shared__ bf16 As[128 * LS];
    __shared__ bf16 Bs[128 * LS];
    const int t = threadIdx.x;
    const int lane = t & 63, wave = t >> 6;
    const int wr = wave >> 1, wc = wave & 1;    // 2x2 wave grid
    const int quad = lane >> 4, l15 = lane & 15;
    const int m0 = blockIdx.y * 128, n0 = blockIdx.x * 128;
    const int srow = t >> 2, scol = (t & 3) * 8;   // staging: 64 rows x 4x8 cols per pass

    f32x4 acc[4][4] = {};

    for (int k0 = 0; k0 < K; k0 += 32) {
        #pragma unroll
        for (int p = 0; p < 2; ++p) {
            int r = srow + p * 64;
            *(bf16x8*)&As[r * LS + scol] = *(const bf16x8*)&X [(size_t)(m0 + r) * K + k0 + scol];
            *(bf16x8*)&Bs[r * LS + scol] = *(const bf16x8*)&WT[(size_t)(n0 + r) * K + k0 + scol];
        }
        __syncthreads();
        bf16x8 a[4], b[4];
        #pragma unroll
        for (int i = 0; i < 4; ++i) {
            a[i] = *(const bf16x8*)&As[(wr * 64 + i * 16 + l15) * LS + quad * 8];
            b[i] = *(const bf16x8*)&Bs[(wc * 64 + i * 16 + l15) * LS + quad * 8];
        }
        #pragma unroll
        for (int i = 0; i < 4; ++i)
            #pragma unroll
            for (int j = 0; j < 4; ++j)
                acc[i][j] = __builtin_amdgcn_mfma_f32_16x16x32_bf16(a[i], b[j], acc[i][j], 0, 0, 0);
        __syncthreads();
    }
    // epilogue: D elem (m = quad*4+reg, n = lane&15) within each 16x16 tile
    #pragma unroll
    for (int j = 0; j < 4; ++j) {
        int n = n0 + wc * 64 + j * 16 + l15;
        float bi = bf2float(bias[n]);
        #pragma unroll
        for (int i = 0; i < 4; ++i) {
            #pragma unroll
            for (int r = 0; r < 4; ++r) {
                int m = m0 + wr * 64 + i * 16 + quad * 4 + r;
                float v = acc[i][j][r] + bi;
                if (RELU) v = fmaxf(v, 0.0f);
                C[(size_t)m * N + n] = __float2bfloat16(v);
            }
        }
    }
}

// ---------------------------------------------------------------- M = max-mean of sampled scores
__launch_bounds__(256)
__global__ void m_kernel(const bf16* __restrict__ Q, const bf16* __restrict__ Kg,
                         const int* __restrict__ sidx, float* __restrict__ Mv)
{
    __shared__ float Qs[64][68];
    __shared__ float Ks[64][132];
    __shared__ float redM[64][16];
    __shared__ float redS[64][16];
    const int t  = threadIdx.x;
    const int bh = blockIdx.y, b = bh >> 3, h = bh & 7;
    const int l0 = blockIdx.x * 64;

    int dl = t & 63, r4 = t >> 6;
    #pragma unroll
    for (int p = 0; p < 16; ++p) {
        int lr = r4 + p * 4;
        Qs[dl][lr] = bf2float(Q[((size_t)(b * Ld + l0 + lr)) * Dd + h * 64 + dl]);
    }
    #pragma unroll
    for (int p = 0; p < 32; ++p) {
        int j = r4 + p * 4;
        Ks[dl][j] = bf2float(Kg[((size_t)(b * Ld + sidx[j])) * Dd + h * 64 + dl]);
    }
    __syncthreads();

    const int tx = t & 15, ty = t >> 4;
    float acc[4][8] = {};
    for (int d = 0; d < 64; ++d) {
        float4 a4  = *(const float4*)&Qs[d][ty * 4];
        float4 b4a = *(const float4*)&Ks[d][tx * 8];
        float4 b4b = *(const float4*)&Ks[d][tx * 8 + 4];
        float av[4] = {a4.x, a4.y, a4.z, a4.w};
        float bv[8] = {b4a.x, b4a.y, b4a.z, b4a.w, b4b.x, b4b.y, b4b.z, b4b.w};
        #pragma unroll
        for (int i = 0; i < 4; ++i)
            #pragma unroll
            for (int j = 0; j < 8; ++j)
                acc[i][j] = fmaf(av[i], bv[j], acc[i][j]);
    }
    #pragma unroll
    for (int i = 0; i < 4; ++i) {
        float rmax = -1e30f, rsum = 0.0f;
        #pragma unroll
        for (int j = 0; j < 8; ++j) { rmax = fmaxf(rmax, acc[i][j]); rsum += acc[i][j]; }
        redM[ty * 4 + i][tx] = rmax;
        redS[ty * 4 + i][tx] = rsum;
    }
    __syncthreads();
    if (t < 64) {
        float m = -1e30f, s = 0.0f;
        #pragma unroll
        for (int q = 0; q < 16; ++q) { m = fmaxf(m, redM[t][q]); s += redS[t][q]; }
        Mv[(size_t)bh * Ld + l0 + t] = m - s * (1.0f / 128.0f);
    }
}

// ---------------------------------------------------------------- top-128 via bitonic sort (desc)
__launch_bounds__(256)
__global__ void topk_kernel(const float* __restrict__ Mv, int* __restrict__ topIdx)
{
    __shared__ float val[4096];
    __shared__ int   idx[4096];
    const int bh = blockIdx.x, t = threadIdx.x;
    for (int i = t; i < 4096; i += 256) { val[i] = Mv[(size_t)bh * Ld + i]; idx[i] = i; }
    __syncthreads();
    for (int k = 2; k <= 4096; k <<= 1) {
        for (int j = k >> 1; j > 0; j >>= 1) {
            for (int i = t; i < 4096; i += 256) {
                int ixj = i ^ j;
                if (ixj > i) {
                    bool up = ((i & k) == 0);
                    float vi = val[i], vj = val[ixj];
                    bool sw = up ? (vi < vj) : (vi > vj);
                    if (sw) {
                        val[i] = vj; val[ixj] = vi;
                        int tmp = idx[i]; idx[i] = idx[ixj]; idx[ixj] = tmp;
                    }
                }
            }
            __syncthreads();
        }
    }
    if (t < Ud) topIdx[bh * Ud + t] = idx[t];
}

// ---------------------------------------------------------------- per-row sparse-entry list
__global__ void rows_kernel(const int* __restrict__ topIdx, int* __restrict__ rowCnt,
                            int* __restrict__ rowEnt)
{
    const int bh = blockIdx.x, u = threadIdx.x, b = bh >> 3;
    const int lq = topIdx[bh * Ud + u];
    const int row = b * Ld + lq;
    int slot = atomicAdd(&rowCnt[row], 1) & 7;
    rowEnt[row * 8 + slot] = bh * Ud + u;
}

// ---------------------------------------------------------------- meanV over L per (b,h,d)
__launch_bounds__(256)
__global__ void meanv_kernel(const bf16* __restrict__ V, float* __restrict__ meanV)
{
    const int bh = blockIdx.x, b = bh >> 3, h = bh & 7, t = threadIdx.x;
    const int d = t & 63, part = t >> 6;
    float s = 0.0f;
    for (int l = part; l < Ld; l += 4)
        s += bf2float(V[((size_t)(b * Ld + l)) * Dd + h * 64 + d]);
    __shared__ float red[256];
    red[t] = s;
    __syncthreads();
    if (t < 64) {
        float tot = red[t] + red[64 + t] + red[128 + t] + red[192 + t];
        meanV[bh * 64 + t] = tot * (1.0f / 4096.0f);
    }
}

// ---------------------------------------------------------------- flash attention (K-split partials)
// grid (4 u-tiles, 64 bh, 8 k-slices); each block: 32 u's x 512 keys.
// Partials: pO = O*exp(-m) unnormalized (bf16), pM/pL per row.
__launch_bounds__(256)
__global__ void attn_kernel(const bf16* __restrict__ Qg, const bf16* __restrict__ Kg,
                            const bf16* __restrict__ Vg, const int* __restrict__ topIdx,
                            bf16* __restrict__ pO, float* __restrict__ pM, float* __restrict__ pL)
{
    __shared__ float Ks[64][68];
    __shared__ float Vs[64][68];
    const int t = threadIdx.x, c = t & 63, w = t >> 6;
    const int ut = blockIdx.x, bh = blockIdx.y, ks = blockIdx.z;
    const int b = bh >> 3, h = bh & 7;

    float Qreg[8];
    #pragma unroll
    for (int rr = 0; rr < 8; ++rr) {
        int u  = ut * 32 + w * 8 + rr;
        int lq = topIdx[bh * Ud + u];
        Qreg[rr] = bf2float(Qg[((size_t)(b * Ld + lq)) * Dd + h * 64 + c]);
    }
    float mrun[8], lrun[8], oacc[8], p[8];
    #pragma unroll
    for (int rr = 0; rr < 8; ++rr) { mrun[rr] = -1e30f; lrun[rr] = 0.0f; oacc[rr] = 0.0f; }

    const int sr = t >> 3, sc8 = (t & 7) * 8;
    for (int kt = ks * 8; kt < ks * 8 + 8; ++kt) {
        #pragma unroll
        for (int pp = 0; pp < 2; ++pp) {
            int r = sr + pp * 32;
            size_t g = ((size_t)(b * Ld + kt * 64 + r)) * Dd + h * 64 + sc8;
            u16x8 kb = *(const u16x8*)&Kg[g];
            u16x8 vb = *(const u16x8*)&Vg[g];
            #pragma unroll
            for (int j = 0; j < 8; ++j) {
                Ks[r][sc8 + j] = __uint_as_float((unsigned)kb[j] << 16);
                Vs[r][sc8 + j] = __uint_as_float((unsigned)vb[j] << 16);
            }
        }
        __syncthreads();

        float s[8] = {};
        for (int d = 0; d < 64; ++d) {
            float kv = Ks[c][d];
            #pragma unroll
            for (int rr = 0; rr < 8; ++rr)
                s[rr] = fmaf(rdlane(Qreg[rr], d), kv, s[rr]);
        }
        #pragma unroll
        for (int rr = 0; rr < 8; ++rr) {
            float sv   = s[rr] * 0.125f;                 // 1/sqrt(64)
            float smax = wred_max(sv);
            float mnew = fmaxf(mrun[rr], smax);
            float pv   = __expf(sv - mnew);
            float psum = wred_sum(pv);
            float alpha = __expf(mrun[rr] - mnew);
            lrun[rr] = lrun[rr] * alpha + psum;
            mrun[rr] = mnew;
            oacc[rr] *= alpha;
            p[rr] = pv;
        }
        for (int c2 = 0; c2 < 64; ++c2) {
            float vv = Vs[c2][c];
            #pragma unroll
            for (int rr = 0; rr < 8; ++rr)
                oacc[rr] = fmaf(rdlane(p[rr], c2), vv, oacc[rr]);
        }
        __syncthreads();
    }
    #pragma unroll
    for (int rr = 0; rr < 8; ++rr) {
        int u = ut * 32 + w * 8 + rr;
        pO[(((size_t)ks * 64 + bh) * Ud + u) * 64 + c] = __float2bfloat16(oacc[rr]);
        if (c == 0) {
            pM[(ks * 64 + bh) * Ud + u] = mrun[rr];
            pL[(ks * 64 + bh) * Ud + u] = lrun[rr];
        }
    }
}

// combine K-split partials -> ctxTop. grid 64*128 blocks of 64 threads.
__global__ void combine_kernel(const bf16* __restrict__ pO, const float* __restrict__ pM,
                               const float* __restrict__ pL, float* __restrict__ ctxTop)
{
    const int u = blockIdx.x & 127, bh = blockIdx.x >> 7, c = threadIdx.x;
    float mstar = -1e30f;
    #pragma unroll
    for (int ks = 0; ks < KSd; ++ks)
        mstar = fmaxf(mstar, pM[(ks * 64 + bh) * Ud + u]);
    float lsum = 0.0f, osum = 0.0f;
    #pragma unroll
    for (int ks = 0; ks < KSd; ++ks) {
        float wgt = __expf(pM[(ks * 64 + bh) * Ud + u] - mstar);
        lsum += pL[(ks * 64 + bh) * Ud + u] * wgt;
        osum += bf2float(pO[(((size_t)ks * 64 + bh) * Ud + u) * 64 + c]) * wgt;
    }
    ctxTop[((size_t)bh * Ud + u) * 64 + c] = scrub(osum / lsum);
}

// ---------------------------------------------------------------- base row: concat(meanV) @ Wo + bo
__launch_bounds__(512)
__global__ void baseout_kernel(const float* __restrict__ meanV, const bf16* __restrict__ Wo,
                               const bf16* __restrict__ bo, float* __restrict__ baseOut)
{
    const int b = blockIdx.x, t = threadIdx.x;
    __shared__ float mv[512];
    mv[t] = meanV[b * 512 + t];
    __syncthreads();
    float acc = bf2float(bo[t]);
    for (int d = 0; d < 512; ++d)
        acc = fmaf(mv[d], bf2float(Wo[(size_t)d * 512 + t]), acc);
    baseOut[b * 512 + t] = acc;
}

// ---------------------------------------------------------------- per-(bh,u) delta rows (bf16 out)
__launch_bounds__(256)
__global__ void delta_kernel(const float* __restrict__ ctxTop, const float* __restrict__ meanV,
                             const bf16* __restrict__ Wo, bf16* __restrict__ deltaOut)
{
    const int u = blockIdx.x, bh = blockIdx.y, h = bh & 7, t = threadIdx.x;
    __shared__ float diff[64];
    if (t < 64) diff[t] = ctxTop[((size_t)bh * Ud + u) * 64 + t] - meanV[bh * 64 + t];
    __syncthreads();
    for (int n = t; n < 512; n += 256) {
        float acc = 0.0f;
        #pragma unroll 8
        for (int dd = 0; dd < 64; ++dd)
            acc = fmaf(diff[dd], bf2float(Wo[(size_t)(h * 64 + dd) * 512 + n]), acc);
        deltaOut[((size_t)bh * Ud + u) * 512 + n] = __float2bfloat16(acc);
    }
}

// ---------------------------------------------------------------- LayerNorms
__launch_bounds__(256)
__global__ void ln1_kernel(const bf16* __restrict__ x, const float* __restrict__ baseOut,
                           const int* __restrict__ rowCnt, const int* __restrict__ rowEnt,
                           const bf16* __restrict__ deltaOut,
                           const bf16* __restrict__ g, const bf16* __restrict__ bb,
                           bf16* __restrict__ x1)
{
    const int row = blockIdx.x, t = threadIdx.x;
    const int b = row >> 12;
    const size_t base = (size_t)row * 512;
    float v0 = bf2float(x[base + t])       + baseOut[b * 512 + t];
    float v1 = bf2float(x[base + t + 256]) + baseOut[b * 512 + t + 256];
    const int cnt = min(rowCnt[row], 8);
    for (int e = 0; e < cnt; ++e) {
        const bf16* dr = &deltaOut[(size_t)rowEnt[row * 8 + e] * 512];
        v0 += bf2float(dr[t]);
        v1 += bf2float(dr[t + 256]);
    }
    v0 = scrub(v0); v1 = scrub(v1);
    float s = v0 + v1, q = v0 * v0 + v1 * v1;
    s = wred_sum(s); q = wred_sum(q);
    __shared__ float sred[4], qred[4];
    int lane = t & 63, w = t >> 6;
    if (lane == 0) { sred[w] = s; qred[w] = q; }
    __syncthreads();
    float tot  = sred[0] + sred[1] + sred[2] + sred[3];
    float totq = qred[0] + qred[1] + qred[2] + qred[3];
    float mean = tot * (1.0f / 512.0f);
    float var  = fmaxf(totq * (1.0f / 512.0f) - mean * mean, 0.0f);
    float rstd = rsqrtf(var + 1e-6f);
    x1[base + t]       = __float2bfloat16((v0 - mean) * rstd * bf2float(g[t])       + bf2float(bb[t]));
    x1[base + t + 256] = __float2bfloat16((v1 - mean) * rstd * bf2float(g[t + 256]) + bf2float(bb[t + 256]));
}

__launch_bounds__(256)
__global__ void ln2_kernel(const bf16* __restrict__ x1, const bf16* __restrict__ ffn,
                           const bf16* __restrict__ g, const bf16* __restrict__ bb,
                           void* __restrict__ out, const int* __restrict__ flags)
{
    const int row = blockIdx.x, t = threadIdx.x;
    const size_t base = (size_t)row * 512;
    float v0 = bf2float(x1[base + t])       + bf2float(ffn[base + t]);
    float v1 = bf2float(x1[base + t + 256]) + bf2float(ffn[base + t + 256]);
    v0 = scrub(v0); v1 = scrub(v1);
    float s = v0 + v1, q = v0 * v0 + v1 * v1;
    s = wred_sum(s); q = wred_sum(q);
    __shared__ float sred[4], qred[4];
    int lane = t & 63, w = t >> 6;
    if (lane == 0) { sred[w] = s; qred[w] = q; }
    __syncthreads();
    float tot  = sred[0] + sred[1] + sred[2] + sred[3];
    float totq = qred[0] + qred[1] + qred[2] + qred[3];
    float mean = tot * (1.0f / 512.0f);
    float var  = fmaxf(totq * (1.0f / 512.0f) - mean * mean, 0.0f);
    float rstd = rsqrtf(var + 1e-6f);
    float o0 = (v0 - mean) * rstd * bf2float(g[t])       + bf2float(bb[t]);
    float o1 = (v1 - mean) * rstd * bf2float(g[t + 256]) + bf2float(bb[t + 256]);
    if (flags[0]) {
        ((float*)out)[base + t]       = o0;
        ((float*)out)[base + t + 256] = o1;
    } else {
        ((bf16*)out)[base + t]       = __float2bfloat16(o0);
        ((bf16*)out)[base + t + 256] = __float2bfloat16(o1);
    }
}

// ================================================================ launcher
extern "C" void kernel_launch(void* const* d_in, const int* in_sizes, int n_in,
                              void* d_out, int out_size, void* d_ws, size_t ws_size,
                              hipStream_t stream)
{
    const void* sraw = d_in[17];

    const size_t NQ = (size_t)MLd * Dd;          // 16,777,216 elements
    char* w = (char*)d_ws;
    size_t off = 0;
    auto alloc = [&](size_t bytes) { void* p = w + off; off += (bytes + 63) & ~size_t(63); return p; };
    bf16*  Qb   = (bf16*)alloc(NQ * 2);                       // 32 MiB
    bf16*  Kb   = (bf16*)alloc(NQ * 2);                       // 32 MiB
    bf16*  Vb   = (bf16*)alloc(NQ * 2);                       // 32 MiB
    bf16*  xc   = (bf16*)alloc(NQ * 2);                       // 32 MiB
    bf16*  WTq  = (bf16*)alloc(Dd * Dd * 2);
    bf16*  WTk  = (bf16*)alloc(Dd * Dd * 2);
    bf16*  WTv  = (bf16*)alloc(Dd * Dd * 2);
    bf16*  Woc  = (bf16*)alloc(Dd * Dd * 2);                  // untransposed
    bf16*  WT1f = (bf16*)alloc((size_t)Dd * DFFd * 2);        // [2048][512]
    bf16*  WT2f = (bf16*)alloc((size_t)DFFd * Dd * 2);        // [512][2048]
    bf16* bqc = (bf16*)alloc(Dd * 2);
    bf16* bkc = (bf16*)alloc(Dd * 2);
    bf16* bvc = (bf16*)alloc(Dd * 2);
    bf16* boc = (bf16*)alloc(Dd * 2);
    bf16* g1c = (bf16*)alloc(Dd * 2);
    bf16* b1c = (bf16*)alloc(Dd * 2);
    bf16* b1fc= (bf16*)alloc(DFFd * 2);
    bf16* b2fc= (bf16*)alloc(Dd * 2);
    bf16* g2c = (bf16*)alloc(Dd * 2);
    bf16* b2c = (bf16*)alloc(Dd * 2);
    bf16*  pOb     = (bf16*)alloc((size_t)KSd * 64 * Ud * 64 * 2);   // 8 MiB
    float* Mv      = (float*)alloc((size_t)Bd * Hd * Ld * 4);        // 1 MiB
    float* ctxTop  = (float*)alloc((size_t)Bd * Hd * Ud * DHd * 4);  // 2 MiB
    float* meanV   = (float*)alloc(Bd * Hd * DHd * 4);
    float* baseOut = (float*)alloc(Bd * Dd * 4);
    int*   topIdx  = (int*)alloc(Bd * Hd * Ud * 4);
    int*   sidx    = (int*)alloc(128 * 4);
    int*   rowCnt  = (int*)alloc(MLd * 4);
    int*   rowEnt  = (int*)alloc(MLd * 8 * 4);
    int*   flags   = (int*)alloc(64);
    // aliases (lifetimes disjoint, stream-serialized):
    bf16*  x1b  = Vb;                 // ln1 output (V dead)
    bf16*  h1b  = Qb;                 // FFN hidden chunk (Q dead)
    bf16*  ffnb = Kb;                 // FFN out (K dead)
    bf16*  deltaOut = pOb;            // after combine_kernel, pO dead (8 MiB == 8 MiB)
    float* pM = Mv;                   // Mv dead after topk
    float* pL = Mv + KSd * 64 * Ud;

    if (off > ws_size) return;

    detect_kernel<<<1, 256, 0, stream>>>(d_in[0], flags);

    auto conv = [&](int i, bf16* dst, int n) {
        conv_kernel<<<(n + 255) / 256, 256, 0, stream>>>(d_in[i], dst, n, flags);
    };
    conv(0,  xc, (int)NQ);
    convT_kernel<<<dim3(Dd / 32, Dd / 32), 256, 0, stream>>>(d_in[1], WTq, Dd, Dd, flags);
    convT_kernel<<<dim3(Dd / 32, Dd / 32), 256, 0, stream>>>(d_in[3], WTk, Dd, Dd, flags);
    convT_kernel<<<dim3(Dd / 32, Dd / 32), 256, 0, stream>>>(d_in[5], WTv, Dd, Dd, flags);
    convT_kernel<<<dim3(DFFd / 32, Dd / 32), 256, 0, stream>>>(d_in[11], WT1f, Dd, DFFd, flags);
    convT_kernel<<<dim3(Dd / 32, DFFd / 32), 256, 0, stream>>>(d_in[13], WT2f, DFFd, Dd, flags);
    conv(7,  Woc, Dd * Dd);
    conv(2,  bqc, Dd);  conv(4,  bkc, Dd);  conv(6,  bvc, Dd);  conv(8,  boc, Dd);
    conv(9,  g1c, Dd);  conv(10, b1c, Dd);
    conv(12, b1fc, DFFd); conv(14, b2fc, Dd);
    conv(15, g2c, Dd);  conv(16, b2c, Dd);

    zero_kernel<<<(MLd + 255) / 256, 256, 0, stream>>>(rowCnt, MLd);
    idx_kernel<<<1, 128, 0, stream>>>(sraw, sidx);

    // QKV projections (MFMA)
    mfma_gemm<false><<<dim3(4, 256), 256, 0, stream>>>(xc, WTq, bqc, Qb, MLd, Dd, Dd);
    mfma_gemm<false><<<dim3(4, 256), 256, 0, stream>>>(xc, WTk, bkc, Kb, MLd, Dd, Dd);
    mfma_gemm<false><<<dim3(4, 256), 256, 0, stream>>>(xc, WTv, bvc, Vb, MLd, Dd, Dd);

    m_kernel<<<dim3(Ld / 64, Bd * Hd), 256, 0, stream>>>(Qb, Kb, sidx, Mv);
    topk_kernel<<<Bd * Hd, 256, 0, stream>>>(Mv, topIdx);
    rows_kernel<<<Bd * Hd, 128, 0, stream>>>(topIdx, rowCnt, rowEnt);
    meanv_kernel<<<Bd * Hd, 256, 0, stream>>>(Vb, meanV);

    attn_kernel<<<dim3(4, Bd * Hd, KSd), 256, 0, stream>>>(Qb, Kb, Vb, topIdx, pOb, pM, pL);
    combine_kernel<<<Bd * Hd * Ud, 64, 0, stream>>>(pOb, pM, pL, ctxTop);

    baseout_kernel<<<Bd, 512, 0, stream>>>(meanV, Woc, boc, baseOut);
    delta_kernel<<<dim3(Ud, Bd * Hd), 256, 0, stream>>>(ctxTop, meanV, Woc, deltaOut);

    ln1_kernel<<<MLd, 256, 0, stream>>>(xc, baseOut, rowCnt, rowEnt, deltaOut, g1c, b1c, x1b);

    // FFN, chunked over rows (h1 chunk = 8192x2048 bf16 aliases Qb)
    for (int c = 0; c < 4; ++c) {
        mfma_gemm<true ><<<dim3(16, 64), 256, 0, stream>>>(
            x1b + (size_t)c * 8192 * 512, WT1f, b1fc, h1b, 8192, DFFd, Dd);
        mfma_gemm<false><<<dim3(4, 64), 256, 0, stream>>>(
            h1b, WT2f, b2fc, ffnb + (size_t)c * 8192 * 512, 8192, Dd, DFFd);
    }

    ln2_kernel<<<MLd, 256, 0, stream>>>(x1b, ffnb, g2c, b2c, d_out, flags);
}

// Round 5
// 1588.264 us; speedup vs baseline: 2.3036x; 1.0070x over previous
//
#include <hip/hip_runtime.h>
#include <hip/hip_bf16.h>

using bf16 = __hip_bfloat16;

constexpr int Bd  = 8;
constexpr int Ld  = 4096;
constexpr int Dd  = 512;
constexpr int Hd  = 8;
constexpr int DHd = 64;
constexpr int DFFd= 2048;
constexpr int Ud  = 128;           // TOP_U
constexpr int MLd = Bd * Ld;       // 32768 rows
constexpr int KSd = 8;             // attention K-split

typedef short          bf16x8 __attribute__((ext_vector_type(8)));
typedef unsigned short u16x8  __attribute__((ext_vector_type(8)));
typedef float          f32x4  __attribute__((ext_vector_type(4)));

__device__ __forceinline__ float bf2float(bf16 v) { return __bfloat162float(v); }

__device__ __forceinline__ float rdlane(float v, int l) {
    return __int_as_float(__builtin_amdgcn_readlane(__float_as_int(v), l));
}
__device__ __forceinline__ float wred_sum(float v) {
    #pragma unroll
    for (int o = 32; o > 0; o >>= 1) v += __shfl_xor(v, o);
    return v;
}
__device__ __forceinline__ float wred_max(float v) {
    #pragma unroll
    for (int o = 32; o > 0; o >>= 1) v = fmaxf(v, __shfl_xor(v, o));
    return v;
}
__device__ __forceinline__ float scrub(float v) {       // NaN/Inf -> 0
    return (fabsf(v) < 1e20f) ? v : 0.0f;
}

// async global->LDS, 16B per lane; LDS dest = wave-uniform base + lane*16
__device__ __forceinline__ void gload_lds16(const bf16* g, bf16* lds_base) {
    __builtin_amdgcn_global_load_lds((const __attribute__((address_space(1))) void*)g,
                                     (__attribute__((address_space(3))) void*)lds_base,
                                     16, 0, 0);
}

// ---------------------------------------------------------------- dtype detector
__global__ void detect_kernel(const void* xraw, int* flags) {
    const unsigned short* u = (const unsigned short*)xraw;
    __shared__ int cnt;
    if (threadIdx.x == 0) cnt = 0;
    __syncthreads();
    int local = 0;
    for (int i = threadIdx.x; i < 1024; i += 256) {
        int e = (u[2 * i] >> 7) & 0xFF;
        if (e >= 96 && e <= 142) local++;
    }
    atomicAdd(&cnt, local);
    __syncthreads();
    if (threadIdx.x == 0) flags[0] = (cnt < 512) ? 1 : 0;
}

// canonicalize any float tensor to bf16
__global__ void conv_kernel(const void* raw, bf16* dst, int n, const int* flags) {
    int i = blockIdx.x * 256 + threadIdx.x;
    if (i >= n) return;
    if (flags[0]) dst[i] = __float2bfloat16(((const float*)raw)[i]);
    else          dst[i] = ((const bf16*)raw)[i];
}

// canonicalize + transpose weight: in W[K][N] -> out WT[N][K] (bf16)
__global__ void convT_kernel(const void* raw, bf16* dst, int K, int N, const int* flags) {
    __shared__ bf16 tile[32][33];
    const int k0 = blockIdx.y * 32, n0 = blockIdx.x * 32;
    const int tx = threadIdx.x & 31, ty = threadIdx.x >> 5;     // 32 x 8
    #pragma unroll
    for (int p = 0; p < 4; ++p) {
        int k = k0 + ty + p * 8, n = n0 + tx;
        float v = flags[0] ? ((const float*)raw)[(size_t)k * N + n]
                           : bf2float(((const bf16*)raw)[(size_t)k * N + n]);
        tile[ty + p * 8][tx] = __float2bfloat16(v);
    }
    __syncthreads();
    #pragma unroll
    for (int p = 0; p < 4; ++p) {
        int n = n0 + ty + p * 8, k = k0 + tx;
        dst[(size_t)n * K + k] = tile[tx][ty + p * 8];
    }
}

__global__ void zero_kernel(int* p, int n) {
    int i = blockIdx.x * 256 + threadIdx.x;
    if (i < n) p[i] = 0;
}

// sample_idx: int32 or int64 device layout; clamped to [0, Ld)
__global__ void idx_kernel(const void* raw, int* out) {
    const int* r32 = (const int*)raw;
    __shared__ int is64;
    int t = threadIdx.x;                       // 128 threads
    if (t == 0) is64 = 1;
    __syncthreads();
    if (t < 64 && r32[2 * t + 1] != 0) is64 = 0;
    __syncthreads();
    int v = is64 ? r32[2 * t] : r32[t];
    out[t] = min(max(v, 0), Ld - 1);
}

// ---------------------------------------------------------------- MFMA GEMM (m97 recipe)
// C[m,n] = sum_k X[m,k]*WT[n,k] + bias[n]; 128x128 tile, BK=32, 4 waves.
// Staging via global_load_lds width-16: unpadded 64B rows (layout constraint
// of wave-uniform-base + lane*16). ds_read_b128 fragment reads take the m97
// bank-conflict tax; MFMA dominates.
template<bool RELU>
__launch_bounds__(256)
__global__ void mfma_gemm(const bf16* __restrict__ X, const bf16* __restrict__ WT,
                          const bf16* __restrict__ bias, bf16* __restrict__ C,
                          int M, int N, int K)
{
    __shared__ bf16 As[128 * 32];
    __shared__ bf16 Bs[128 * 32];
    const int t = threadIdx.x;
    const int lane = t & 63, wave = t >> 6;
    const int wr = wave >> 1, wc = wave & 1;    // 2x2 wave grid
    const int quad = lane >> 4, l15 = lane & 15;
    const int m0 = blockIdx.y * 128, n0 = blockIdx.x * 128;
    const int lrow = lane >> 2, lcol = (lane & 3) * 8;   // 16 rows x 4x8 cols per wave-load

    f32x4 acc[4][4] = {};

    for (int k0 = 0; k0 < K; k0 += 32) {
        #pragma unroll
        for (int p = 0; p < 2; ++p) {
            int r0 = wave * 16 + p * 64;
            gload_lds16(&X [(size_t)(m0 + r0 + lrow) * K + k0 + lcol], &As[r0 * 32]);
            gload_lds16(&WT[(size_t)(n0 + r0 + lrow) * K + k0 + lcol], &Bs[r0 * 32]);
        }
        __syncthreads();
        bf16x8 a[4], b[4];
        #pragma unroll
        for (int i = 0; i < 4; ++i) {
            a[i] = *(const bf16x8*)&As[(wr * 64 + i * 16 + l15) * 32 + quad * 8];
            b[i] = *(const bf16x8*)&Bs[(wc * 64 + i * 16 + l15) * 32 + quad * 8];
        }
        #pragma unroll
        for (int i = 0; i < 4; ++i)
            #pragma unroll
            for (int j = 0; j < 4; ++j)
                acc[i][j] = __builtin_amdgcn_mfma_f32_16x16x32_bf16(a[i], b[j], acc[i][j], 0, 0, 0);
        __syncthreads();
    }
    // epilogue: D elem (m = quad*4+reg, n = lane&15) within each 16x16 tile
    #pragma unroll
    for (int j = 0; j < 4; ++j) {
        int n = n0 + wc * 64 + j * 16 + l15;
        float bi = bf2float(bias[n]);
        #pragma unroll
        for (int i = 0; i < 4; ++i) {
            #pragma unroll
            for (int r = 0; r < 4; ++r) {
                int m = m0 + wr * 64 + i * 16 + quad * 4 + r;
                float v = acc[i][j][r] + bi;
                if (RELU) v = fmaxf(v, 0.0f);
                C[(size_t)m * N + n] = __float2bfloat16(v);
            }
        }
    }
}

// ---------------------------------------------------------------- M = max-mean of sampled scores
__launch_bounds__(256)
__global__ void m_kernel(const bf16* __restrict__ Q, const bf16* __restrict__ Kg,
                         const int* __restrict__ sidx, float* __restrict__ Mv)
{
    __shared__ float Qs[64][68];
    __shared__ float Ks[64][132];
    __shared__ float redM[64][16];
    __shared__ float redS[64][16];
    const int t  = threadIdx.x;
    const int bh = blockIdx.y, b = bh >> 3, h = bh & 7;
    const int l0 = blockIdx.x * 64;

    int dl = t & 63, r4 = t >> 6;
    #pragma unroll
    for (int p = 0; p < 16; ++p) {
        int lr = r4 + p * 4;
        Qs[dl][lr] = bf2float(Q[((size_t)(b * Ld + l0 + lr)) * Dd + h * 64 + dl]);
    }
    #pragma unroll
    for (int p = 0; p < 32; ++p) {
        int j = r4 + p * 4;
        Ks[dl][j] = bf2float(Kg[((size_t)(b * Ld + sidx[j])) * Dd + h * 64 + dl]);
    }
    __syncthreads();

    const int tx = t & 15, ty = t >> 4;
    float acc[4][8] = {};
    for (int d = 0; d < 64; ++d) {
        float4 a4  = *(const float4*)&Qs[d][ty * 4];
        float4 b4a = *(const float4*)&Ks[d][tx * 8];
        float4 b4b = *(const float4*)&Ks[d][tx * 8 + 4];
        float av[4] = {a4.x, a4.y, a4.z, a4.w};
        float bv[8] = {b4a.x, b4a.y, b4a.z, b4a.w, b4b.x, b4b.y, b4b.z, b4b.w};
        #pragma unroll
        for (int i = 0; i < 4; ++i)
            #pragma unroll
            for (int j = 0; j < 8; ++j)
                acc[i][j] = fmaf(av[i], bv[j], acc[i][j]);
    }
    #pragma unroll
    for (int i = 0; i < 4; ++i) {
        float rmax = -1e30f, rsum = 0.0f;
        #pragma unroll
        for (int j = 0; j < 8; ++j) { rmax = fmaxf(rmax, acc[i][j]); rsum += acc[i][j]; }
        redM[ty * 4 + i][tx] = rmax;
        redS[ty * 4 + i][tx] = rsum;
    }
    __syncthreads();
    if (t < 64) {
        float m = -1e30f, s = 0.0f;
        #pragma unroll
        for (int q = 0; q < 16; ++q) { m = fmaxf(m, redM[t][q]); s += redS[t][q]; }
        Mv[(size_t)bh * Ld + l0 + t] = m - s * (1.0f / 128.0f);
    }
}

// ---------------------------------------------------------------- top-128 via bitonic sort (desc)
__launch_bounds__(256)
__global__ void topk_kernel(const float* __restrict__ Mv, int* __restrict__ topIdx)
{
    __shared__ float val[4096];
    __shared__ int   idx[4096];
    const int bh = blockIdx.x, t = threadIdx.x;
    for (int i = t; i < 4096; i += 256) { val[i] = Mv[(size_t)bh * Ld + i]; idx[i] = i; }
    __syncthreads();
    for (int k = 2; k <= 4096; k <<= 1) {
        for (int j = k >> 1; j > 0; j >>= 1) {
            for (int i = t; i < 4096; i += 256) {
                int ixj = i ^ j;
                if (ixj > i) {
                    bool up = ((i & k) == 0);
                    float vi = val[i], vj = val[ixj];
                    bool sw = up ? (vi < vj) : (vi > vj);
                    if (sw) {
                        val[i] = vj; val[ixj] = vi;
                        int tmp = idx[i]; idx[i] = idx[ixj]; idx[ixj] = tmp;
                    }
                }
            }
            __syncthreads();
        }
    }
    if (t < Ud) topIdx[bh * Ud + t] = idx[t];
}

// ---------------------------------------------------------------- per-row sparse-entry list
__global__ void rows_kernel(const int* __restrict__ topIdx, int* __restrict__ rowCnt,
                            int* __restrict__ rowEnt)
{
    const int bh = blockIdx.x, u = threadIdx.x, b = bh >> 3;
    const int lq = topIdx[bh * Ud + u];
    const int row = b * Ld + lq;
    int slot = atomicAdd(&rowCnt[row], 1) & 7;
    rowEnt[row * 8 + slot] = bh * Ud + u;
}

// ---------------------------------------------------------------- meanV over L per (b,h,d)
__launch_bounds__(256)
__global__ void meanv_kernel(const bf16* __restrict__ V, float* __restrict__ meanV)
{
    const int bh = blockIdx.x, b = bh >> 3, h = bh & 7, t = threadIdx.x;
    const int d = t & 63, part = t >> 6;
    float s = 0.0f;
    for (int l = part; l < Ld; l += 4)
        s += bf2float(V[((size_t)(b * Ld + l)) * Dd + h * 64 + d]);
    __shared__ float red[256];
    red[t] = s;
    __syncthreads();
    if (t < 64) {
        float tot = red[t] + red[64 + t] + red[128 + t] + red[192 + t];
        meanV[bh * 64 + t] = tot * (1.0f / 4096.0f);
    }
}

// ---------------------------------------------------------------- flash attention (K-split partials)
// LDS stride 65: QK read Ks[c][d] -> bank (c+d)%32, 2-way (free); PV read
// Vs[c2][c] also 2-way. (Round-4's stride 68 gave 8-way, 4.19e6 conflicts.)
__launch_bounds__(256)
__global__ void attn_kernel(const bf16* __restrict__ Qg, const bf16* __restrict__ Kg,
                            const bf16* __restrict__ Vg, const int* __restrict__ topIdx,
                            bf16* __restrict__ pO, float* __restrict__ pM, float* __restrict__ pL)
{
    __shared__ float Ks[64][65];
    __shared__ float Vs[64][65];
    const int t = threadIdx.x, c = t & 63, w = t >> 6;
    const int ut = blockIdx.x, bh = blockIdx.y, ks = blockIdx.z;
    const int b = bh >> 3, h = bh & 7;

    float Qreg[8];
    #pragma unroll
    for (int rr = 0; rr < 8; ++rr) {
        int u  = ut * 32 + w * 8 + rr;
        int lq = topIdx[bh * Ud + u];
        Qreg[rr] = bf2float(Qg[((size_t)(b * Ld + lq)) * Dd + h * 64 + c]);
    }
    float mrun[8], lrun[8], oacc[8], p[8];
    #pragma unroll
    for (int rr = 0; rr < 8; ++rr) { mrun[rr] = -1e30f; lrun[rr] = 0.0f; oacc[rr] = 0.0f; }

    const int sr = t >> 3, sc8 = (t & 7) * 8;
    for (int kt = ks * 8; kt < ks * 8 + 8; ++kt) {
        #pragma unroll
        for (int pp = 0; pp < 2; ++pp) {
            int r = sr + pp * 32;
            size_t g = ((size_t)(b * Ld + kt * 64 + r)) * Dd + h * 64 + sc8;
            u16x8 kb = *(const u16x8*)&Kg[g];
            u16x8 vb = *(const u16x8*)&Vg[g];
            #pragma unroll
            for (int j = 0; j < 8; ++j) {
                Ks[r][sc8 + j] = __uint_as_float((unsigned)kb[j] << 16);
                Vs[r][sc8 + j] = __uint_as_float((unsigned)vb[j] << 16);
            }
        }
        __syncthreads();

        float s[8] = {};
        for (int d = 0; d < 64; ++d) {
            float kv = Ks[c][d];
            #pragma unroll
            for (int rr = 0; rr < 8; ++rr)
                s[rr] = fmaf(rdlane(Qreg[rr], d), kv, s[rr]);
        }
        #pragma unroll
        for (int rr = 0; rr < 8; ++rr) {
            float sv   = s[rr] * 0.125f;                 // 1/sqrt(64)
            float smax = wred_max(sv);
            float mnew = fmaxf(mrun[rr], smax);
            float pv   = __expf(sv - mnew);
            float psum = wred_sum(pv);
            float alpha = __expf(mrun[rr] - mnew);
            lrun[rr] = lrun[rr] * alpha + psum;
            mrun[rr] = mnew;
            oacc[rr] *= alpha;
            p[rr] = pv;
        }
        for (int c2 = 0; c2 < 64; ++c2) {
            float vv = Vs[c2][c];
            #pragma unroll
            for (int rr = 0; rr < 8; ++rr)
                oacc[rr] = fmaf(rdlane(p[rr], c2), vv, oacc[rr]);
        }
        __syncthreads();
    }
    #pragma unroll
    for (int rr = 0; rr < 8; ++rr) {
        int u = ut * 32 + w * 8 + rr;
        pO[(((size_t)ks * 64 + bh) * Ud + u) * 64 + c] = __float2bfloat16(oacc[rr]);
        if (c == 0) {
            pM[(ks * 64 + bh) * Ud + u] = mrun[rr];
            pL[(ks * 64 + bh) * Ud + u] = lrun[rr];
        }
    }
}

// combine K-split partials -> ctxTop
__global__ void combine_kernel(const bf16* __restrict__ pO, const float* __restrict__ pM,
                               const float* __restrict__ pL, float* __restrict__ ctxTop)
{
    const int u = blockIdx.x & 127, bh = blockIdx.x >> 7, c = threadIdx.x;
    float mstar = -1e30f;
    #pragma unroll
    for (int ks = 0; ks < KSd; ++ks)
        mstar = fmaxf(mstar, pM[(ks * 64 + bh) * Ud + u]);
    float lsum = 0.0f, osum = 0.0f;
    #pragma unroll
    for (int ks = 0; ks < KSd; ++ks) {
        float wgt = __expf(pM[(ks * 64 + bh) * Ud + u] - mstar);
        lsum += pL[(ks * 64 + bh) * Ud + u] * wgt;
        osum += bf2float(pO[(((size_t)ks * 64 + bh) * Ud + u) * 64 + c]) * wgt;
    }
    ctxTop[((size_t)bh * Ud + u) * 64 + c] = scrub(osum / lsum);
}

// ---------------------------------------------------------------- base row: concat(meanV) @ Wo + bo
__launch_bounds__(512)
__global__ void baseout_kernel(const float* __restrict__ meanV, const bf16* __restrict__ Wo,
                               const bf16* __restrict__ bo, float* __restrict__ baseOut)
{
    const int b = blockIdx.x, t = threadIdx.x;
    __shared__ float mv[512];
    mv[t] = meanV[b * 512 + t];
    __syncthreads();
    float acc = bf2float(bo[t]);
    for (int d = 0; d < 512; ++d)
        acc = fmaf(mv[d], bf2float(Wo[(size_t)d * 512 + t]), acc);
    baseOut[b * 512 + t] = acc;
}

// ---------------------------------------------------------------- per-(bh,u) delta rows (bf16 out)
__launch_bounds__(256)
__global__ void delta_kernel(const float* __restrict__ ctxTop, const float* __restrict__ meanV,
                             const bf16* __restrict__ Wo, bf16* __restrict__ deltaOut)
{
    const int u = blockIdx.x, bh = blockIdx.y, h = bh & 7, t = threadIdx.x;
    __shared__ float diff[64];
    if (t < 64) diff[t] = ctxTop[((size_t)bh * Ud + u) * 64 + t] - meanV[bh * 64 + t];
    __syncthreads();
    for (int n = t; n < 512; n += 256) {
        float acc = 0.0f;
        #pragma unroll 8
        for (int dd = 0; dd < 64; ++dd)
            acc = fmaf(diff[dd], bf2float(Wo[(size_t)(h * 64 + dd) * 512 + n]), acc);
        deltaOut[((size_t)bh * Ud + u) * 512 + n] = __float2bfloat16(acc);
    }
}

// ---------------------------------------------------------------- LayerNorms
__launch_bounds__(256)
__global__ void ln1_kernel(const bf16* __restrict__ x, const float* __restrict__ baseOut,
                           const int* __restrict__ rowCnt, const int* __restrict__ rowEnt,
                           const bf16* __restrict__ deltaOut,
                           const bf16* __restrict__ g, const bf16* __restrict__ bb,
                           bf16* __restrict__ x1)
{
    const int row = blockIdx.x, t = threadIdx.x;
    const int b = row >> 12;
    const size_t base = (size_t)row * 512;
    float v0 = bf2float(x[base + t])       + baseOut[b * 512 + t];
    float v1 = bf2float(x[base + t + 256]) + baseOut[b * 512 + t + 256];
    const int cnt = min(rowCnt[row], 8);
    for (int e = 0; e < cnt; ++e) {
        const bf16* dr = &deltaOut[(size_t)rowEnt[row * 8 + e] * 512];
        v0 += bf2float(dr[t]);
        v1 += bf2float(dr[t + 256]);
    }
    v0 = scrub(v0); v1 = scrub(v1);
    float s = v0 + v1, q = v0 * v0 + v1 * v1;
    s = wred_sum(s); q = wred_sum(q);
    __shared__ float sred[4], qred[4];
    int lane = t & 63, w = t >> 6;
    if (lane == 0) { sred[w] = s; qred[w] = q; }
    __syncthreads();
    float tot  = sred[0] + sred[1] + sred[2] + sred[3];
    float totq = qred[0] + qred[1] + qred[2] + qred[3];
    float mean = tot * (1.0f / 512.0f);
    float var  = fmaxf(totq * (1.0f / 512.0f) - mean * mean, 0.0f);
    float rstd = rsqrtf(var + 1e-6f);
    x1[base + t]       = __float2bfloat16((v0 - mean) * rstd * bf2float(g[t])       + bf2float(bb[t]));
    x1[base + t + 256] = __float2bfloat16((v1 - mean) * rstd * bf2float(g[t + 256]) + bf2float(bb[t + 256]));
}

__launch_bounds__(256)
__global__ void ln2_kernel(const bf16* __restrict__ x1, const bf16* __restrict__ ffn,
                           const bf16* __restrict__ g, const bf16* __restrict__ bb,
                           void* __restrict__ out, const int* __restrict__ flags)
{
    const int row = blockIdx.x, t = threadIdx.x;
    const size_t base = (size_t)row * 512;
    float v0 = bf2float(x1[base + t])       + bf2float(ffn[base + t]);
    float v1 = bf2float(x1[base + t + 256]) + bf2float(ffn[base + t + 256]);
    v0 = scrub(v0); v1 = scrub(v1);
    float s = v0 + v1, q = v0 * v0 + v1 * v1;
    s = wred_sum(s); q = wred_sum(q);
    __shared__ float sred[4], qred[4];
    int lane = t & 63, w = t >> 6;
    if (lane == 0) { sred[w] = s; qred[w] = q; }
    __syncthreads();
    float tot  = sred[0] + sred[1] + sred[2] + sred[3];
    float totq = qred[0] + qred[1] + qred[2] + qred[3];
    float mean = tot * (1.0f / 512.0f);
    float var  = fmaxf(totq * (1.0f / 512.0f) - mean * mean, 0.0f);
    float rstd = rsqrtf(var + 1e-6f);
    float o0 = (v0 - mean) * rstd * bf2float(g[t])       + bf2float(bb[t]);
    float o1 = (v1 - mean) * rstd * bf2float(g[t + 256]) + bf2float(bb[t + 256]);
    if (flags[0]) {
        ((float*)out)[base + t]       = o0;
        ((float*)out)[base + t + 256] = o1;
    } else {
        ((bf16*)out)[base + t]       = __float2bfloat16(o0);
        ((bf16*)out)[base + t + 256] = __float2bfloat16(o1);
    }
}

// ================================================================ launcher
extern "C" void kernel_launch(void* const* d_in, const int* in_sizes, int n_in,
                              void* d_out, int out_size, void* d_ws, size_t ws_size,
                              hipStream_t stream)
{
    const void* sraw = d_in[17];

    const size_t NQ = (size_t)MLd * Dd;          // 16,777,216 elements
    char* w = (char*)d_ws;
    size_t off = 0;
    auto alloc = [&](size_t bytes) { void* p = w + off; off += (bytes + 63) & ~size_t(63); return p; };
    bf16*  Qb   = (bf16*)alloc(NQ * 2);                       // 32 MiB
    bf16*  Kb   = (bf16*)alloc(NQ * 2);                       // 32 MiB
    bf16*  Vb   = (bf16*)alloc(NQ * 2);                       // 32 MiB
    bf16*  xc   = (bf16*)alloc(NQ * 2);                       // 32 MiB
    bf16*  WTq  = (bf16*)alloc(Dd * Dd * 2);
    bf16*  WTk  = (bf16*)alloc(Dd * Dd * 2);
    bf16*  WTv  = (bf16*)alloc(Dd * Dd * 2);
    bf16*  Woc  = (bf16*)alloc(Dd * Dd * 2);                  // untransposed
    bf16*  WT1f = (bf16*)alloc((size_t)Dd * DFFd * 2);        // [2048][512]
    bf16*  WT2f = (bf16*)alloc((size_t)DFFd * Dd * 2);        // [512][2048]
    bf16* bqc = (bf16*)alloc(Dd * 2);
    bf16* bkc = (bf16*)alloc(Dd * 2);
    bf16* bvc = (bf16*)alloc(Dd * 2);
    bf16* boc = (bf16*)alloc(Dd * 2);
    bf16* g1c = (bf16*)alloc(Dd * 2);
    bf16* b1c = (bf16*)alloc(Dd * 2);
    bf16* b1fc= (bf16*)alloc(DFFd * 2);
    bf16* b2fc= (bf16*)alloc(Dd * 2);
    bf16* g2c = (bf16*)alloc(Dd * 2);
    bf16* b2c = (bf16*)alloc(Dd * 2);
    bf16*  pOb     = (bf16*)alloc((size_t)KSd * 64 * Ud * 64 * 2);   // 8 MiB
    float* Mv      = (float*)alloc((size_t)Bd * Hd * Ld * 4);        // 1 MiB
    float* ctxTop  = (float*)alloc((size_t)Bd * Hd * Ud * DHd * 4);  // 2 MiB
    float* meanV   = (float*)alloc(Bd * Hd * DHd * 4);
    float* baseOut = (float*)alloc(Bd * Dd * 4);
    int*   topIdx  = (int*)alloc(Bd * Hd * Ud * 4);
    int*   sidx    = (int*)alloc(128 * 4);
    int*   rowCnt  = (int*)alloc(MLd * 4);
    int*   rowEnt  = (int*)alloc(MLd * 8 * 4);
    int*   flags   = (int*)alloc(64);
    // aliases (lifetimes disjoint, stream-serialized):
    bf16*  x1b  = Vb;                 // ln1 output (V dead)
    bf16*  h1b  = Qb;                 // FFN hidden chunk (Q dead)
    bf16*  ffnb = Kb;                 // FFN out (K dead)
    bf16*  deltaOut = pOb;            // after combine_kernel, pO dead
    float* pM = Mv;                   // Mv dead after topk
    float* pL = Mv + KSd * 64 * Ud;

    if (off > ws_size) return;

    detect_kernel<<<1, 256, 0, stream>>>(d_in[0], flags);

    auto conv = [&](int i, bf16* dst, int n) {
        conv_kernel<<<(n + 255) / 256, 256, 0, stream>>>(d_in[i], dst, n, flags);
    };
    conv(0,  xc, (int)NQ);
    convT_kernel<<<dim3(Dd / 32, Dd / 32), 256, 0, stream>>>(d_in[1], WTq, Dd, Dd, flags);
    convT_kernel<<<dim3(Dd / 32, Dd / 32), 256, 0, stream>>>(d_in[3], WTk, Dd, Dd, flags);
    convT_kernel<<<dim3(Dd / 32, Dd / 32), 256, 0, stream>>>(d_in[5], WTv, Dd, Dd, flags);
    convT_kernel<<<dim3(DFFd / 32, Dd / 32), 256, 0, stream>>>(d_in[11], WT1f, Dd, DFFd, flags);
    convT_kernel<<<dim3(Dd / 32, DFFd / 32), 256, 0, stream>>>(d_in[13], WT2f, DFFd, Dd, flags);
    conv(7,  Woc, Dd * Dd);
    conv(2,  bqc, Dd);  conv(4,  bkc, Dd);  conv(6,  bvc, Dd);  conv(8,  boc, Dd);
    conv(9,  g1c, Dd);  conv(10, b1c, Dd);
    conv(12, b1fc, DFFd); conv(14, b2fc, Dd);
    conv(15, g2c, Dd);  conv(16, b2c, Dd);

    zero_kernel<<<(MLd + 255) / 256, 256, 0, stream>>>(rowCnt, MLd);
    idx_kernel<<<1, 128, 0, stream>>>(sraw, sidx);

    // QKV projections (MFMA, async-staged)
    mfma_gemm<false><<<dim3(4, 256), 256, 0, stream>>>(xc, WTq, bqc, Qb, MLd, Dd, Dd);
    mfma_gemm<false><<<dim3(4, 256), 256, 0, stream>>>(xc, WTk, bkc, Kb, MLd, Dd, Dd);
    mfma_gemm<false><<<dim3(4, 256), 256, 0, stream>>>(xc, WTv, bvc, Vb, MLd, Dd, Dd);

    m_kernel<<<dim3(Ld / 64, Bd * Hd), 256, 0, stream>>>(Qb, Kb, sidx, Mv);
    topk_kernel<<<Bd * Hd, 256, 0, stream>>>(Mv, topIdx);
    rows_kernel<<<Bd * Hd, 128, 0, stream>>>(topIdx, rowCnt, rowEnt);
    meanv_kernel<<<Bd * Hd, 256, 0, stream>>>(Vb, meanV);

    attn_kernel<<<dim3(4, Bd * Hd, KSd), 256, 0, stream>>>(Qb, Kb, Vb, topIdx, pOb, pM, pL);
    combine_kernel<<<Bd * Hd * Ud, 64, 0, stream>>>(pOb, pM, pL, ctxTop);

    baseout_kernel<<<Bd, 512, 0, stream>>>(meanV, Woc, boc, baseOut);
    delta_kernel<<<dim3(Ud, Bd * Hd), 256, 0, stream>>>(ctxTop, meanV, Woc, deltaOut);

    ln1_kernel<<<MLd, 256, 0, stream>>>(xc, baseOut, rowCnt, rowEnt, deltaOut, g1c, b1c, x1b);

    // FFN, chunked over rows (h1 chunk = 8192x2048 bf16 aliases Qb)
    for (int c = 0; c < 4; ++c) {
        mfma_gemm<true ><<<dim3(16, 64), 256, 0, stream>>>(
            x1b + (size_t)c * 8192 * 512, WT1f, b1fc, h1b, 8192, DFFd, Dd);
        mfma_gemm<false><<<dim3(4, 64), 256, 0, stream>>>(
            h1b, WT2f, b2fc, ffnb + (size_t)c * 8192 * 512, 8192, Dd, DFFd);
    }

    ln2_kernel<<<MLd, 256, 0, stream>>>(x1b, ffnb, g2c, b2c, d_out, flags);
}